// Round 1
// baseline (254.855 us; speedup 1.0000x reference)
//
#include <hip/hip_runtime.h>
#include <stdint.h>

// ---------------- types ----------------
typedef short bf16x8 __attribute__((ext_vector_type(8)));
typedef float f32x4  __attribute__((ext_vector_type(4)));

__device__ __forceinline__ uint16_t f2bf(float f) {
    uint32_t u = __float_as_uint(f);
    u += 0x7FFF + ((u >> 16) & 1);   // round-to-nearest-even
    return (uint16_t)(u >> 16);
}

// ---------------- prologue: fp32 -> bf16 transposed weights ----------------
// out[e][c][r] = bf16(in[e][r][c]);  in: [E][R][C] fp32, out: [E][C][R] bf16
__global__ void transpose_bf16(const float* __restrict__ in, uint16_t* __restrict__ out,
                               int R, int C) {
    __shared__ float t[32][33];
    const int tx = threadIdx.x, ty = threadIdx.y;
    const int r0 = blockIdx.y * 32, c0 = blockIdx.x * 32;
    const float* ine = in + (size_t)blockIdx.z * R * C;
    uint16_t* oute   = out + (size_t)blockIdx.z * R * C;
#pragma unroll
    for (int j = 0; j < 4; ++j)
        t[ty + 8 * j][tx] = ine[(size_t)(r0 + ty + 8 * j) * C + (c0 + tx)];
    __syncthreads();
#pragma unroll
    for (int j = 0; j < 4; ++j) {
        int orow = c0 + ty + 8 * j;   // output row = input col
        int ocol = r0 + tx;           // output col = input row
        oute[(size_t)orow * R + ocol] = f2bf(t[tx][ty + 8 * j]);
    }
}

// ---------------- fused ensemble MLP ----------------
// LDS layout: [0,64K) = H1 tile (64x512 bf16, swizzled)
//             [64K,128K) = union{ X tile (64x256 bf16, 32K), H2 tile (64x512 bf16) }
#define H1_OFF   0
#define BUF2_OFF 65536

// One 64-row x 512-col dense layer: per-wave 64 output cols (n0 = wid*64),
// all 64 rows. A from swizzled LDS, B (bf16, [512][K] row-major) from global.
template <int K, bool RELU>
__device__ __forceinline__ void dense64(const char* __restrict__ smemA, int aStride,
                                        const uint16_t* __restrict__ Bg,
                                        const float* __restrict__ bias,
                                        char* __restrict__ smemO,
                                        int wid, int lane) {
    const int kg = lane >> 4, lr = lane & 15;
    const int n0 = wid * 64;

    f32x4 acc[4][4];
#pragma unroll
    for (int r = 0; r < 4; ++r)
#pragma unroll
        for (int c = 0; c < 4; ++c) acc[r][c] = f32x4{0.f, 0.f, 0.f, 0.f};

    auto ldA = [&](int r, int k0) -> bf16x8 {
        const int row  = 16 * r + lr;
        const int byte = row * aStride + ((((k0 + kg * 8) << 1)) ^ ((row & 7) << 4));
        return *(const bf16x8*)(smemA + byte);
    };
    auto ldB = [&](int c, int k0) -> bf16x8 {
        const int n = n0 + 16 * c + lr;
        return *(const bf16x8*)(Bg + n * K + k0 + kg * 8);
    };

    bf16x8 a0[4], b0[4], a1[4], b1[4];
#pragma unroll
    for (int r = 0; r < 4; ++r) a0[r] = ldA(r, 0);
#pragma unroll
    for (int c = 0; c < 4; ++c) b0[c] = ldB(c, 0);

    for (int k0 = 0; k0 < K; k0 += 64) {   // K % 64 == 0 always (256 or 512)
#pragma unroll
        for (int r = 0; r < 4; ++r) a1[r] = ldA(r, k0 + 32);
#pragma unroll
        for (int c = 0; c < 4; ++c) b1[c] = ldB(c, k0 + 32);
#pragma unroll
        for (int r = 0; r < 4; ++r)
#pragma unroll
            for (int c = 0; c < 4; ++c)
                acc[r][c] = __builtin_amdgcn_mfma_f32_16x16x32_bf16(a0[r], b0[c], acc[r][c], 0, 0, 0);
        if (k0 + 64 < K) {
#pragma unroll
            for (int r = 0; r < 4; ++r) a0[r] = ldA(r, k0 + 64);
#pragma unroll
            for (int c = 0; c < 4; ++c) b0[c] = ldB(c, k0 + 64);
        }
#pragma unroll
        for (int r = 0; r < 4; ++r)
#pragma unroll
            for (int c = 0; c < 4; ++c)
                acc[r][c] = __builtin_amdgcn_mfma_f32_16x16x32_bf16(a1[r], b1[c], acc[r][c], 0, 0, 0);
    }

    // epilogue: bias + (relu) + bf16 -> swizzled LDS (row stride 1024B)
    float bv[4];
#pragma unroll
    for (int c = 0; c < 4; ++c) bv[c] = bias[n0 + 16 * c + lr];
#pragma unroll
    for (int r = 0; r < 4; ++r)
#pragma unroll
        for (int c = 0; c < 4; ++c)
#pragma unroll
            for (int v = 0; v < 4; ++v) {
                const int row = 16 * r + kg * 4 + v;
                const int col = n0 + 16 * c + lr;
                float x = acc[r][c][v] + bv[c];
                if (RELU) x = fmaxf(x, 0.f);
                *(uint16_t*)(smemO + row * 1024 + (((col << 1)) ^ ((row & 7) << 4))) = f2bf(x);
            }
}

__global__ __launch_bounds__(512, 2) void fused_mlp(
    const float* __restrict__ X,
    const uint16_t* __restrict__ W1T, const float* __restrict__ b1,
    const uint16_t* __restrict__ W2T, const float* __restrict__ b2,
    const uint16_t* __restrict__ W3T, const float* __restrict__ b3,
    float* __restrict__ out) {
    extern __shared__ char smem[];
    const int tid = threadIdx.x, wid = tid >> 6, lane = tid & 63;
    const int e  = blockIdx.x & 7;          // XCD round-robin -> per-XCD weight locality
    const int b0 = (blockIdx.x >> 3) * 64;  // row block

    // ---- stage X tile [64][256] fp32 -> bf16 swizzled LDS ----
#pragma unroll
    for (int it = 0; it < 8; ++it) {
        const int idx = it * 512 + tid;
        const int row = idx >> 6;
        const int col = (idx & 63) << 2;
        const float4 xv = *(const float4*)(X + (size_t)(b0 + row) * 256 + col);
        ushort4 h;
        h.x = f2bf(xv.x); h.y = f2bf(xv.y); h.z = f2bf(xv.z); h.w = f2bf(xv.w);
        *(ushort4*)(smem + BUF2_OFF + row * 512 + (((col << 1)) ^ ((row & 7) << 4))) = h;
    }
    __syncthreads();

    // ---- layer 1: h1 = relu(X @ W1 + b1), K=256 ----
    dense64<256, true>(smem + BUF2_OFF, 512, W1T + e * (512 * 256), b1 + e * 512,
                       smem + H1_OFF, wid, lane);
    __syncthreads();

    // ---- layer 2: h2 = relu(h1 @ W2 + b2), K=512 ----
    dense64<512, true>(smem + H1_OFF, 1024, W2T + e * (512 * 512), b2 + e * 512,
                       smem + BUF2_OFF, wid, lane);
    __syncthreads();

    // ---- layer 3: out = h2 @ W3 + b3  (64x32, K=512) ----
    {
        const int kg = lane >> 4, lr = lane & 15;
        const int r3 = wid >> 1, c3 = wid & 1;   // 4 row-groups x 2 col-groups
        f32x4 acc = f32x4{0.f, 0.f, 0.f, 0.f};
        const uint16_t* Bg = W3T + e * (32 * 512) + (16 * c3 + lr) * 512 + kg * 8;
        const char* Abase = smem + BUF2_OFF;
        const int rowA = 16 * r3 + lr;
        const int aB = rowA * 1024;
        const int aX = (rowA & 7) << 4;
#pragma unroll
        for (int k0 = 0; k0 < 512; k0 += 32) {
            bf16x8 a = *(const bf16x8*)(Abase + aB + ((((k0 + kg * 8) << 1)) ^ aX));
            bf16x8 b = *(const bf16x8*)(Bg + k0);
            acc = __builtin_amdgcn_mfma_f32_16x16x32_bf16(a, b, acc, 0, 0, 0);
        }
        const float bb = b3[e * 32 + 16 * c3 + lr];
#pragma unroll
        for (int v = 0; v < 4; ++v) {
            const int rg = b0 + 16 * r3 + kg * 4 + v;
            out[(size_t)rg * 256 + e * 32 + 16 * c3 + lr] = acc[v] + bb;
        }
    }
}

// ---------------- host launch ----------------
extern "C" void kernel_launch(void* const* d_in, const int* in_sizes, int n_in,
                              void* d_out, int out_size, void* d_ws, size_t ws_size,
                              hipStream_t stream) {
    const float* X  = (const float*)d_in[0];   // [16384,256]
    const float* W1 = (const float*)d_in[1];   // [8,256,512]
    const float* b1 = (const float*)d_in[2];   // [8,512]
    const float* W2 = (const float*)d_in[3];   // [8,512,512]
    const float* b2 = (const float*)d_in[4];   // [8,512]
    const float* W3 = (const float*)d_in[5];   // [8,512,32]
    const float* b3 = (const float*)d_in[6];   // [8,32]
    float* out = (float*)d_out;                // [16384,8,32]

    uint16_t* w1t = (uint16_t*)d_ws;           // [8][512][256] bf16
    uint16_t* w2t = w1t + 8 * 256 * 512;       // [8][512][512] bf16
    uint16_t* w3t = w2t + 8 * 512 * 512;       // [8][32][512]  bf16

    dim3 blk(32, 8);
    transpose_bf16<<<dim3(512 / 32, 256 / 32, 8), blk, 0, stream>>>(W1, w1t, 256, 512);
    transpose_bf16<<<dim3(512 / 32, 512 / 32, 8), blk, 0, stream>>>(W2, w2t, 512, 512);
    transpose_bf16<<<dim3(32 / 32, 512 / 32, 8),  blk, 0, stream>>>(W3, w3t, 512, 32);

    (void)hipFuncSetAttribute((const void*)fused_mlp,
                              hipFuncAttributeMaxDynamicSharedMemorySize, 131072);
    fused_mlp<<<2048, 512, 131072, stream>>>(X, w1t, b1, w2t, b2, w3t, b3, out);
}